// Round 13
// baseline (148.865 us; speedup 1.0000x reference)
//
#include <hip/hip_runtime.h>
#include <math.h>

// Problem constants
#define NBATCH   32768
#define OWN_DIM  7
#define INTR_DIM 5
#define N_HEADS  3
#define HEAD_DIM 5
#define N_INTR   256
#define ROWLEN   1287   // OWN_DIM + N_INTR*INTR_DIM
#define XDIM     22     // OWN_DIM + N_HEADS*HEAD_DIM
#define H1DIM    256
#define H2DIM    256

#define WDW      384    // staged dwords per row per window (covers 320-dword window + 7 offset)

typedef __attribute__((ext_vector_type(8))) short bf16x8;
typedef __attribute__((ext_vector_type(4))) float f32x4;

__device__ __forceinline__ float leaky02(float x) {
    return fmaxf(x, 0.2f * x);
}

__device__ __forceinline__ unsigned short f2bf_rne(float f) {
    unsigned u = __float_as_uint(f);
    return (unsigned short)((u + 0x7FFFu + ((u >> 16) & 1u)) >> 16);
}

// async global->LDS DMA, width 4B/lane: dest = lds + lane*4 (wave-uniform base),
// src per-lane. Zero VGPR staging cost — this is the whole point (r11 failed
// on VGPR budget; the allocator pins ~64 regs regardless of launch bounds).
__device__ __forceinline__ void gload_lds4(const float* g, float* l) {
    __builtin_amdgcn_global_load_lds(
        (const __attribute__((address_space(1))) void*)g,
        (__attribute__((address_space(3)))  void*)l, 4, 0, 0);
}

// ---------------- Kernel A: attention + layernorm -> x (B x 22) ----------------
// 4 samples/wave (16 lanes each), 16 samples/block.
// r10 ablation: loads = 70 of 86 us (stride-20B pattern = 1600 line-req/wave).
// r11: reg-staged coalescing spilled (VGPR=64 cap). r12: dwordx4 split by
// compiler (align 4 < 16). This round: global_load_lds DMA staging —
// lane-contiguous 256B/inst (24 insts/window/wave, ~340 line-req/wave total),
// zero register cost, intra-wave LDS region (no barriers). vmcnt(0)+sched_barrier
// before LDS reads; lgkmcnt(0) before buffer reuse. Math identical.
__global__ __launch_bounds__(256, 4) void attn_ln_kernel(
    const float* __restrict__ obs,
    const float* __restrict__ Wq, const float* __restrict__ bq,
    const float* __restrict__ Wk, const float* __restrict__ bk,
    const float* __restrict__ Wv, const float* __restrict__ bv,
    const float* __restrict__ v_att, const float* __restrict__ temp,
    const float* __restrict__ ln_g, const float* __restrict__ ln_b,
    float* __restrict__ xout)
{
    __shared__ float smem[4][4][WDW];   // [wave][row][window dwords] = 24.6 KB
    const int wid  = threadIdx.x >> 6;
    const int lane = threadIdx.x & 63;
    const int grp  = lane >> 4;     // sample slot within wave (0..3)
    const int gl   = lane & 15;     // lane within 16-lane sample group
    const int s    = blockIdx.x * 16 + wid * 4 + grp;
    const float* row  = obs + (size_t)s * ROWLEN;                          // compute sample
    const float* wrow = obs + (size_t)(blockIdx.x * 16 + wid * 4) * ROWLEN; // wave's row 0

    const float fac = fabsf(temp[0]) * 0.4472135954999579f;      // |T|/sqrt(5)
    const float facl2e = fac * 1.4426950408889634f;              // * log2e
    const float TL2E = 2.885390081777927f;                       // 2*log2e

    // own[0..6] of this lane's sample (broadcast per group) — issued pre-DMA
    float own[OWN_DIM];
    #pragma unroll
    for (int o = 0; o < OWN_DIM; ++o) own[o] = row[o];

    // per-head score constants: va2 = -2*facl2e*v_att, vasum = facl2e*sum(v_att)
    float va2[N_HEADS][HEAD_DIM], vasum[N_HEADS];
    #pragma unroll
    for (int h = 0; h < N_HEADS; ++h) {
        float ssum = 0.0f;
        #pragma unroll
        for (int d = 0; d < HEAD_DIM; ++d) {
            float v = v_att[h*HEAD_DIM + d];
            ssum += v;
            va2[h][d] = v * (-2.0f * facl2e);
        }
        vasum[h] = ssum * facl2e;
    }

    // qb[h][d] = q + bk for this lane's sample
    float qb[N_HEADS][HEAD_DIM];
    #pragma unroll
    for (int h = 0; h < N_HEADS; ++h)
        #pragma unroll
        for (int d = 0; d < HEAD_DIM; ++d) {
            float a = bq[h*HEAD_DIM + d] + bk[h*HEAD_DIM + d];
            #pragma unroll
            for (int o = 0; o < OWN_DIM; ++o)
                a = fmaf(own[o], Wq[h*OWN_DIM*HEAD_DIM + o*HEAD_DIM + d], a);
            qb[h][d] = a;
        }

    // accumulators
    float svp[N_HEADS][INTR_DIM] = {};
    float es[N_HEADS] = {};

    #pragma unroll
    for (int c = 0; c < 4; ++c) {
        // drain LDS reads of previous window before overwriting the buffer
        if (c > 0) {
            asm volatile("s_waitcnt lgkmcnt(0)" ::: "memory");
            __builtin_amdgcn_sched_barrier(0);
        }
        // issue 24 DMAs: 4 rows x 6 insts, lane-contiguous 256B each
        #pragma unroll
        for (int r = 0; r < 4; ++r) {
            const float* rbase = wrow + (size_t)r * ROWLEN + c * 320;
            #pragma unroll
            for (int j = 0; j < 6; ++j) {
                int idx = j * 64 + lane;
                if (c == 3 && j == 5) idx = (idx > 326) ? 326 : idx;  // row tail clamp
                gload_lds4(rbase + idx, &smem[wid][r][j * 64]);
            }
        }
        // wait for this window's DMA to land in LDS
        asm volatile("s_waitcnt vmcnt(0)" ::: "memory");
        __builtin_amdgcn_sched_barrier(0);

        // compute 4 items of window c from LDS (stride-5 -> 2-way, free)
        const float* win = smem[wid][grp];
        #pragma unroll
        for (int rr = 0; rr < 4; ++rr) {
            const int off = 7 + (gl + 16 * rr) * INTR_DIM;   // window-local dword
            float xi[INTR_DIM];
            #pragma unroll
            for (int i = 0; i < INTR_DIM; ++i) xi[i] = win[off + i];
            float asum = fabsf(xi[0]) + fabsf(xi[1]) + fabsf(xi[2])
                       + fabsf(xi[3]) + fabsf(xi[4]);
            const float npf = (asum < 1e-6f) ? 0.0f : 1.0f;
            #pragma unroll
            for (int h = 0; h < N_HEADS; ++h) {
                float dot = vasum[h];
                #pragma unroll
                for (int d = 0; d < HEAD_DIM; ++d) {
                    float t = qb[h][d];
                    #pragma unroll
                    for (int i = 0; i < INTR_DIM; ++i)
                        t = fmaf(xi[i], Wk[h*INTR_DIM*HEAD_DIM + i*HEAD_DIM + d], t);
                    float e = __builtin_amdgcn_exp2f(t * TL2E);
                    float rc = __builtin_amdgcn_rcpf(e + 1.0f);
                    dot = fmaf(va2[h][d], rc, dot);     // == facl2e*sum va*tanh
                }
                float e = npf * __builtin_amdgcn_exp2f(dot);
                es[h] += e;
                #pragma unroll
                for (int i = 0; i < INTR_DIM; ++i)
                    svp[h][i] = fmaf(e, xi[i], svp[h][i]);
            }
        }
    }

    // 4-level butterfly within each 16-lane group (18 values)
    #pragma unroll
    for (int o = 1; o < 16; o <<= 1) {
        #pragma unroll
        for (int h = 0; h < N_HEADS; ++h) {
            es[h] += __shfl_xor(es[h], o, 64);
            #pragma unroll
            for (int i = 0; i < INTR_DIM; ++i)
                svp[h][i] += __shfl_xor(svp[h][i], o, 64);
        }
    }

    // normalize + deferred V projection: ctx = (svp/es) @ Wv + bv*live
    float ctx[N_HEADS][HEAD_DIM];
    #pragma unroll
    for (int h = 0; h < N_HEADS; ++h) {
        const float live = (es[h] > 0.0f) ? 1.0f : 0.0f;
        const float rinv = live * __builtin_amdgcn_rcpf(es[h]);
        float svn[INTR_DIM];
        #pragma unroll
        for (int i = 0; i < INTR_DIM; ++i) svn[i] = svp[h][i] * rinv;
        #pragma unroll
        for (int d = 0; d < HEAD_DIM; ++d) {
            float c = bv[h*HEAD_DIM + d] * live;
            #pragma unroll
            for (int i = 0; i < INTR_DIM; ++i)
                c = fmaf(svn[i], Wv[h*INTR_DIM*HEAD_DIM + i*HEAD_DIM + d], c);
            ctx[h][d] = c;
        }
    }

    // layernorm over x = [own(7), ctx(15)] (redundant across the 16 group lanes)
    float sum = 0.0f;
    #pragma unroll
    for (int o = 0; o < OWN_DIM; ++o) sum += own[o];
    #pragma unroll
    for (int h = 0; h < N_HEADS; ++h)
        #pragma unroll
        for (int d = 0; d < HEAD_DIM; ++d) sum += ctx[h][d];
    const float mu = sum * (1.0f / 22.0f);
    float var = 0.0f;
    #pragma unroll
    for (int o = 0; o < OWN_DIM; ++o) { float dd = own[o] - mu; var += dd*dd; }
    #pragma unroll
    for (int h = 0; h < N_HEADS; ++h)
        #pragma unroll
        for (int d = 0; d < HEAD_DIM; ++d) { float dd = ctx[h][d] - mu; var += dd*dd; }
    var *= (1.0f / 22.0f);
    const float rs = rsqrtf(var + 1e-5f);

    // lane gl writes elements gl and gl+16 (if <22) via static select chains
    float xv0 = own[0];
    #pragma unroll
    for (int o = 1; o < OWN_DIM; ++o) xv0 = (gl == o) ? own[o] : xv0;
    #pragma unroll
    for (int j = 0; j < 15; ++j) xv0 = (gl == OWN_DIM + j) ? ctx[j/5][j%5] : xv0;
    float xv1 = ctx[1][4];                    // element 16 -> ctx j=9
    #pragma unroll
    for (int j = 10; j < 15; ++j) xv1 = (gl == j - 9) ? ctx[j/5][j%5] : xv1;

    float* xo = xout + (size_t)s * XDIM;
    xo[gl] = (xv0 - mu) * rs * ln_g[gl] + ln_b[gl];
    if (gl < XDIM - 16) {
        xo[16 + gl] = (xv1 - mu) * rs * ln_g[16 + gl] + ln_b[16 + gl];
    }
}

// ---------------- Kernel B: MLP 22->256->256->2 (+log_std) ----------------
// (unchanged — 4.4 us, MFMA layer-2, verified round 5)
__global__ __launch_bounds__(256) void mlp_kernel(
    const float* __restrict__ x,
    const float* __restrict__ W1, const float* __restrict__ b1,
    const float* __restrict__ W2, const float* __restrict__ b2,
    const float* __restrict__ Wf, const float* __restrict__ bf,
    const float* __restrict__ lstd, float* __restrict__ out)
{
    __shared__ __align__(16) float xs[32 * XDIM];
    __shared__ __align__(16) unsigned char h1b[32 * 256 * 2];
    __shared__ __align__(16) unsigned char w2b[256 * 64 * 2];
    __shared__ __align__(16) float wfs[H2DIM * 2];
    __shared__ float oacc[4][32][2];

    const int t   = threadIdx.x;
    const int blk = blockIdx.x;

    for (int i = t; i < 32 * XDIM; i += 256) xs[i] = x[(size_t)blk * 32 * XDIM + i];
    for (int i = t; i < H2DIM * 2; i += 256) wfs[i] = Wf[i];

    float w1r[XDIM];
    #pragma unroll
    for (int i = 0; i < XDIM; ++i) w1r[i] = W1[i * H1DIM + t];
    const float b1t = b1[t];
    __syncthreads();
    for (int e = 0; e < 32; ++e) {
        float a = b1t;
        #pragma unroll
        for (int i = 0; i < XDIM; ++i) a += xs[e * XDIM + i] * w1r[i];
        a = leaky02(a);
        int byte = e * 512 + t * 2;
        byte ^= ((e & 7) << 4);
        *(unsigned short*)(h1b + byte) = f2bf_rne(a);
    }

    const int wv_  = t >> 6;
    const int lane = t & 63;
    const int mrow = lane & 15;
    const int qk   = lane >> 4;

    f32x4 acc[2][4];
    #pragma unroll
    for (int mt = 0; mt < 2; ++mt)
        #pragma unroll
        for (int nt = 0; nt < 4; ++nt)
            acc[mt][nt] = (f32x4){0.f, 0.f, 0.f, 0.f};

    for (int kc = 0; kc < 4; ++kc) {
        __syncthreads();
        {
            const int n = t;
            #pragma unroll
            for (int k8 = 0; k8 < 64; k8 += 8) {
                bf16x8 v;
                #pragma unroll
                for (int j = 0; j < 8; ++j) {
                    float w = W2[(size_t)(kc * 64 + k8 + j) * H2DIM + n];
                    v[j] = (short)f2bf_rne(w);
                }
                int byte = n * 128 + k8 * 2;
                byte ^= ((n & 7) << 4);
                *(bf16x8*)(w2b + byte) = v;
            }
        }
        __syncthreads();
        #pragma unroll
        for (int ks = 0; ks < 2; ++ks) {
            const int klocal = ks * 32;
            const int kglob  = kc * 64 + klocal;
            bf16x8 afrag[2], bfrag[4];
            #pragma unroll
            for (int mt = 0; mt < 2; ++mt) {
                const int rowi = mt * 16 + mrow;
                int byte = rowi * 512 + (kglob + 8 * qk) * 2;
                byte ^= ((rowi & 7) << 4);
                afrag[mt] = *(const bf16x8*)(h1b + byte);
            }
            #pragma unroll
            for (int nt = 0; nt < 4; ++nt) {
                const int col = wv_ * 64 + nt * 16 + mrow;
                int byte = col * 128 + (klocal + 8 * qk) * 2;
                byte ^= ((col & 7) << 4);
                bfrag[nt] = *(const bf16x8*)(w2b + byte);
            }
            #pragma unroll
            for (int mt = 0; mt < 2; ++mt)
                #pragma unroll
                for (int nt = 0; nt < 4; ++nt)
                    acc[mt][nt] = __builtin_amdgcn_mfma_f32_16x16x32_bf16(
                        afrag[mt], bfrag[nt], acc[mt][nt], 0, 0, 0);
        }
    }

    float b2n[4];
    #pragma unroll
    for (int nt = 0; nt < 4; ++nt) b2n[nt] = b2[wv_ * 64 + nt * 16 + mrow];

    float p[8][2];
    #pragma unroll
    for (int i = 0; i < 8; ++i) { p[i][0] = 0.f; p[i][1] = 0.f; }
    #pragma unroll
    for (int mt = 0; mt < 2; ++mt)
        #pragma unroll
        for (int nt = 0; nt < 4; ++nt) {
            const int n = wv_ * 64 + nt * 16 + mrow;
            #pragma unroll
            for (int reg = 0; reg < 4; ++reg) {
                float h2v = leaky02(acc[mt][nt][reg] + b2n[nt]);
                p[mt*4 + reg][0] = fmaf(h2v, wfs[2*n + 0], p[mt*4 + reg][0]);
                p[mt*4 + reg][1] = fmaf(h2v, wfs[2*n + 1], p[mt*4 + reg][1]);
            }
        }
    #pragma unroll
    for (int o = 1; o < 16; o <<= 1) {
        #pragma unroll
        for (int i = 0; i < 8; ++i) {
            p[i][0] += __shfl_xor(p[i][0], o, 64);
            p[i][1] += __shfl_xor(p[i][1], o, 64);
        }
    }
    if (mrow == 0) {
        #pragma unroll
        for (int mt = 0; mt < 2; ++mt)
            #pragma unroll
            for (int reg = 0; reg < 4; ++reg) {
                const int sample = mt * 16 + qk * 4 + reg;
                oacc[wv_][sample][0] = p[mt*4 + reg][0];
                oacc[wv_][sample][1] = p[mt*4 + reg][1];
            }
    }
    __syncthreads();
    if (t < 32) {
        float o0 = bf[0], o1 = bf[1];
        #pragma unroll
        for (int w = 0; w < 4; ++w) { o0 += oacc[w][t][0]; o1 += oacc[w][t][1]; }
        float4 o4;
        o4.x = o0; o4.y = o1; o4.z = lstd[0]; o4.w = lstd[1];
        *(float4*)&out[(size_t)(blk * 32 + t) * 4] = o4;
    }
}

extern "C" void kernel_launch(void* const* d_in, const int* in_sizes, int n_in,
                              void* d_out, int out_size, void* d_ws, size_t ws_size,
                              hipStream_t stream) {
    const float* obs   = (const float*)d_in[0];
    const float* Wq    = (const float*)d_in[1];
    const float* bq    = (const float*)d_in[2];
    const float* Wk    = (const float*)d_in[3];
    const float* bk    = (const float*)d_in[4];
    const float* Wv    = (const float*)d_in[5];
    const float* bv    = (const float*)d_in[6];
    const float* v_att = (const float*)d_in[7];
    const float* temp  = (const float*)d_in[8];
    const float* ln_g  = (const float*)d_in[9];
    const float* ln_b  = (const float*)d_in[10];
    const float* W1    = (const float*)d_in[11];
    const float* b1    = (const float*)d_in[12];
    const float* W2    = (const float*)d_in[13];
    const float* b2    = (const float*)d_in[14];
    const float* Wf    = (const float*)d_in[15];
    const float* bf    = (const float*)d_in[16];
    const float* lstd  = (const float*)d_in[17];

    float* xbuf = (float*)d_ws;   // B x 22 normalized features (2.88 MB)
    float* outf = (float*)d_out;

    attn_ln_kernel<<<NBATCH / 16, 256, 0, stream>>>(
        obs, Wq, bq, Wk, bk, Wv, bv, v_att, temp, ln_g, ln_b, xbuf);
    mlp_kernel<<<NBATCH / 32, 256, 0, stream>>>(
        xbuf, W1, b1, W2, b2, Wf, bf, lstd, outf);
}

// Round 14
// 107.066 us; speedup vs baseline: 1.3904x; 1.3904x over previous
//
#include <hip/hip_runtime.h>
#include <math.h>

// Problem constants
#define NBATCH   32768
#define OWN_DIM  7
#define INTR_DIM 5
#define N_HEADS  3
#define HEAD_DIM 5
#define N_INTR   256
#define ROWLEN   1287   // OWN_DIM + N_INTR*INTR_DIM
#define XDIM     22     // OWN_DIM + N_HEADS*HEAD_DIM
#define H1DIM    256
#define H2DIM    256

#define RSTRIDE  336    // LDS row stride: 336 % 32 == 16 -> adjacent rows 16-bank
                        // offset -> stride-5 group reads alias exactly 2-way (free)

typedef __attribute__((ext_vector_type(8))) short bf16x8;
typedef __attribute__((ext_vector_type(4))) float f32x4;

__device__ __forceinline__ float leaky02(float x) {
    return fmaxf(x, 0.2f * x);
}

__device__ __forceinline__ unsigned short f2bf_rne(float f) {
    unsigned u = __float_as_uint(f);
    return (unsigned short)((u + 0x7FFFu + ((u >> 16) & 1u)) >> 16);
}

// ---------------- Kernel A: attention + layernorm -> x (B x 22) ----------------
// 4 samples/wave (16 lanes each), 16 samples/block.
// Load-path history: direct stride-20B loads = 20 line-req/inst x 80 = 85us TA
// cost (r10 ablation, arithmetic exact); reg-staging spilled (r11); dwordx4
// split on align4 (r12); global_load_lds DMA serialized + TCC double-traffic +
// 4-way conflicts (r13). This round: WAVE-LOCAL windowed staging — each wave
// copies its 4 rows' 64-item window (320 dwords, lane-consecutive -> ~5
// lines/inst) into LDS with conflict-free ds_writes, then computes from LDS
// (2-way alias = free). No barriers (intra-wave). Single 21.5KB buffer -> 7
// blocks/CU = 28 waves/CU TLP hides the per-wave stage<->compute serialization.
// Compute/weights/LN identical to the proven 86us kernel; weights stay direct
// global (s_load path — r5 lesson).
__global__ __launch_bounds__(256, 4) void attn_ln_kernel(
    const float* __restrict__ obs,
    const float* __restrict__ Wq, const float* __restrict__ bq,
    const float* __restrict__ Wk, const float* __restrict__ bk,
    const float* __restrict__ Wv, const float* __restrict__ bv,
    const float* __restrict__ v_att, const float* __restrict__ temp,
    const float* __restrict__ ln_g, const float* __restrict__ ln_b,
    float* __restrict__ xout)
{
    __shared__ float sbuf[16][RSTRIDE];   // 21504 B
    const int wid  = threadIdx.x >> 6;
    const int lane = threadIdx.x & 63;
    const int grp  = lane >> 4;     // sample slot within wave (0..3)
    const int gl   = lane & 15;     // lane within 16-lane sample group
    const int s    = blockIdx.x * 16 + wid * 4 + grp;
    const float* row   = obs + (size_t)s * ROWLEN;                           // this lane's sample
    const float* rbase = obs + (size_t)(blockIdx.x * 16 + wid * 4) * ROWLEN; // wave's row 0

    const float fac = fabsf(temp[0]) * 0.4472135954999579f;      // |T|/sqrt(5)
    const float facl2e = fac * 1.4426950408889634f;              // * log2e
    const float TL2E = 2.885390081777927f;                       // 2*log2e

    // own[0..6] of this lane's sample (16-way broadcast per group)
    float own[OWN_DIM];
    #pragma unroll
    for (int o = 0; o < OWN_DIM; ++o) own[o] = row[o];

    // per-head score constants: va2 = -2*facl2e*v_att, vasum = facl2e*sum(v_att)
    float va2[N_HEADS][HEAD_DIM], vasum[N_HEADS];
    #pragma unroll
    for (int h = 0; h < N_HEADS; ++h) {
        float ssum = 0.0f;
        #pragma unroll
        for (int d = 0; d < HEAD_DIM; ++d) {
            float v = v_att[h*HEAD_DIM + d];
            ssum += v;
            va2[h][d] = v * (-2.0f * facl2e);
        }
        vasum[h] = ssum * facl2e;
    }

    // qb[h][d] = q + bk for this lane's sample
    float qb[N_HEADS][HEAD_DIM];
    #pragma unroll
    for (int h = 0; h < N_HEADS; ++h)
        #pragma unroll
        for (int d = 0; d < HEAD_DIM; ++d) {
            float a = bq[h*HEAD_DIM + d] + bk[h*HEAD_DIM + d];
            #pragma unroll
            for (int o = 0; o < OWN_DIM; ++o)
                a = fmaf(own[o], Wq[h*OWN_DIM*HEAD_DIM + o*HEAD_DIM + d], a);
            qb[h][d] = a;
        }

    // accumulators
    float svp[N_HEADS][INTR_DIM] = {};
    float es[N_HEADS] = {};

    const float* win = &sbuf[wid * 4 + grp][0];

    #pragma unroll
    for (int c = 0; c < 4; ++c) {
        // ---- stage this wave's 4 rows, window c: 320 dwords each, coalesced ----
        // (intra-wave only: the wave writes exactly the rows its groups read;
        //  same-wave DS ordering + compiler lgkm waits give correctness, no barrier)
        #pragma unroll
        for (int rr = 0; rr < 4; ++rr) {
            const float* src = rbase + (size_t)rr * ROWLEN + 7 + c * 320;
            float* dst = &sbuf[wid * 4 + rr][0];
            #pragma unroll
            for (int jj = 0; jj < 5; ++jj)
                dst[jj * 64 + lane] = src[jj * 64 + lane];
        }

        // ---- compute 4 items of window c from LDS (stride-5, 2-way = free) ----
        #pragma unroll
        for (int rr = 0; rr < 4; ++rr) {
            const int off = 5 * (gl + 16 * rr);   // window-local item base
            float xi[INTR_DIM];
            #pragma unroll
            for (int i = 0; i < INTR_DIM; ++i) xi[i] = win[off + i];
            float asum = fabsf(xi[0]) + fabsf(xi[1]) + fabsf(xi[2])
                       + fabsf(xi[3]) + fabsf(xi[4]);
            const float npf = (asum < 1e-6f) ? 0.0f : 1.0f;
            #pragma unroll
            for (int h = 0; h < N_HEADS; ++h) {
                float dot = vasum[h];
                #pragma unroll
                for (int d = 0; d < HEAD_DIM; ++d) {
                    float t = qb[h][d];
                    #pragma unroll
                    for (int i = 0; i < INTR_DIM; ++i)
                        t = fmaf(xi[i], Wk[h*INTR_DIM*HEAD_DIM + i*HEAD_DIM + d], t);
                    float e = __builtin_amdgcn_exp2f(t * TL2E);
                    float rc = __builtin_amdgcn_rcpf(e + 1.0f);
                    dot = fmaf(va2[h][d], rc, dot);     // == facl2e*sum va*tanh
                }
                float e = npf * __builtin_amdgcn_exp2f(dot);
                es[h] += e;
                #pragma unroll
                for (int i = 0; i < INTR_DIM; ++i)
                    svp[h][i] = fmaf(e, xi[i], svp[h][i]);
            }
        }
    }

    // 4-level butterfly within each 16-lane group (18 values)
    #pragma unroll
    for (int o = 1; o < 16; o <<= 1) {
        #pragma unroll
        for (int h = 0; h < N_HEADS; ++h) {
            es[h] += __shfl_xor(es[h], o, 64);
            #pragma unroll
            for (int i = 0; i < INTR_DIM; ++i)
                svp[h][i] += __shfl_xor(svp[h][i], o, 64);
        }
    }

    // normalize + deferred V projection: ctx = (svp/es) @ Wv + bv*live
    float ctx[N_HEADS][HEAD_DIM];
    #pragma unroll
    for (int h = 0; h < N_HEADS; ++h) {
        const float live = (es[h] > 0.0f) ? 1.0f : 0.0f;
        const float rinv = live * __builtin_amdgcn_rcpf(es[h]);
        float svn[INTR_DIM];
        #pragma unroll
        for (int i = 0; i < INTR_DIM; ++i) svn[i] = svp[h][i] * rinv;
        #pragma unroll
        for (int d = 0; d < HEAD_DIM; ++d) {
            float c = bv[h*HEAD_DIM + d] * live;
            #pragma unroll
            for (int i = 0; i < INTR_DIM; ++i)
                c = fmaf(svn[i], Wv[h*INTR_DIM*HEAD_DIM + i*HEAD_DIM + d], c);
            ctx[h][d] = c;
        }
    }

    // layernorm over x = [own(7), ctx(15)] (redundant across the 16 group lanes)
    float sum = 0.0f;
    #pragma unroll
    for (int o = 0; o < OWN_DIM; ++o) sum += own[o];
    #pragma unroll
    for (int h = 0; h < N_HEADS; ++h)
        #pragma unroll
        for (int d = 0; d < HEAD_DIM; ++d) sum += ctx[h][d];
    const float mu = sum * (1.0f / 22.0f);
    float var = 0.0f;
    #pragma unroll
    for (int o = 0; o < OWN_DIM; ++o) { float dd = own[o] - mu; var += dd*dd; }
    #pragma unroll
    for (int h = 0; h < N_HEADS; ++h)
        #pragma unroll
        for (int d = 0; d < HEAD_DIM; ++d) { float dd = ctx[h][d] - mu; var += dd*dd; }
    var *= (1.0f / 22.0f);
    const float rs = rsqrtf(var + 1e-5f);

    // lane gl writes elements gl and gl+16 (if <22) via static select chains
    float xv0 = own[0];
    #pragma unroll
    for (int o = 1; o < OWN_DIM; ++o) xv0 = (gl == o) ? own[o] : xv0;
    #pragma unroll
    for (int j = 0; j < 15; ++j) xv0 = (gl == OWN_DIM + j) ? ctx[j/5][j%5] : xv0;
    float xv1 = ctx[1][4];                    // element 16 -> ctx j=9
    #pragma unroll
    for (int j = 10; j < 15; ++j) xv1 = (gl == j - 9) ? ctx[j/5][j%5] : xv1;

    float* xo = xout + (size_t)s * XDIM;
    xo[gl] = (xv0 - mu) * rs * ln_g[gl] + ln_b[gl];
    if (gl < XDIM - 16) {
        xo[16 + gl] = (xv1 - mu) * rs * ln_g[16 + gl] + ln_b[16 + gl];
    }
}

// ---------------- Kernel B: MLP 22->256->256->2 (+log_std) ----------------
// (unchanged — 4.4 us, MFMA layer-2, verified round 5)
__global__ __launch_bounds__(256) void mlp_kernel(
    const float* __restrict__ x,
    const float* __restrict__ W1, const float* __restrict__ b1,
    const float* __restrict__ W2, const float* __restrict__ b2,
    const float* __restrict__ Wf, const float* __restrict__ bf,
    const float* __restrict__ lstd, float* __restrict__ out)
{
    __shared__ __align__(16) float xs[32 * XDIM];
    __shared__ __align__(16) unsigned char h1b[32 * 256 * 2];
    __shared__ __align__(16) unsigned char w2b[256 * 64 * 2];
    __shared__ __align__(16) float wfs[H2DIM * 2];
    __shared__ float oacc[4][32][2];

    const int t   = threadIdx.x;
    const int blk = blockIdx.x;

    for (int i = t; i < 32 * XDIM; i += 256) xs[i] = x[(size_t)blk * 32 * XDIM + i];
    for (int i = t; i < H2DIM * 2; i += 256) wfs[i] = Wf[i];

    float w1r[XDIM];
    #pragma unroll
    for (int i = 0; i < XDIM; ++i) w1r[i] = W1[i * H1DIM + t];
    const float b1t = b1[t];
    __syncthreads();
    for (int e = 0; e < 32; ++e) {
        float a = b1t;
        #pragma unroll
        for (int i = 0; i < XDIM; ++i) a += xs[e * XDIM + i] * w1r[i];
        a = leaky02(a);
        int byte = e * 512 + t * 2;
        byte ^= ((e & 7) << 4);
        *(unsigned short*)(h1b + byte) = f2bf_rne(a);
    }

    const int wv_  = t >> 6;
    const int lane = t & 63;
    const int mrow = lane & 15;
    const int qk   = lane >> 4;

    f32x4 acc[2][4];
    #pragma unroll
    for (int mt = 0; mt < 2; ++mt)
        #pragma unroll
        for (int nt = 0; nt < 4; ++nt)
            acc[mt][nt] = (f32x4){0.f, 0.f, 0.f, 0.f};

    for (int kc = 0; kc < 4; ++kc) {
        __syncthreads();
        {
            const int n = t;
            #pragma unroll
            for (int k8 = 0; k8 < 64; k8 += 8) {
                bf16x8 v;
                #pragma unroll
                for (int j = 0; j < 8; ++j) {
                    float w = W2[(size_t)(kc * 64 + k8 + j) * H2DIM + n];
                    v[j] = (short)f2bf_rne(w);
                }
                int byte = n * 128 + k8 * 2;
                byte ^= ((n & 7) << 4);
                *(bf16x8*)(w2b + byte) = v;
            }
        }
        __syncthreads();
        #pragma unroll
        for (int ks = 0; ks < 2; ++ks) {
            const int klocal = ks * 32;
            const int kglob  = kc * 64 + klocal;
            bf16x8 afrag[2], bfrag[4];
            #pragma unroll
            for (int mt = 0; mt < 2; ++mt) {
                const int rowi = mt * 16 + mrow;
                int byte = rowi * 512 + (kglob + 8 * qk) * 2;
                byte ^= ((rowi & 7) << 4);
                afrag[mt] = *(const bf16x8*)(h1b + byte);
            }
            #pragma unroll
            for (int nt = 0; nt < 4; ++nt) {
                const int col = wv_ * 64 + nt * 16 + mrow;
                int byte = col * 128 + (klocal + 8 * qk) * 2;
                byte ^= ((col & 7) << 4);
                bfrag[nt] = *(const bf16x8*)(w2b + byte);
            }
            #pragma unroll
            for (int mt = 0; mt < 2; ++mt)
                #pragma unroll
                for (int nt = 0; nt < 4; ++nt)
                    acc[mt][nt] = __builtin_amdgcn_mfma_f32_16x16x32_bf16(
                        afrag[mt], bfrag[nt], acc[mt][nt], 0, 0, 0);
        }
    }

    float b2n[4];
    #pragma unroll
    for (int nt = 0; nt < 4; ++nt) b2n[nt] = b2[wv_ * 64 + nt * 16 + mrow];

    float p[8][2];
    #pragma unroll
    for (int i = 0; i < 8; ++i) { p[i][0] = 0.f; p[i][1] = 0.f; }
    #pragma unroll
    for (int mt = 0; mt < 2; ++mt)
        #pragma unroll
        for (int nt = 0; nt < 4; ++nt) {
            const int n = wv_ * 64 + nt * 16 + mrow;
            #pragma unroll
            for (int reg = 0; reg < 4; ++reg) {
                float h2v = leaky02(acc[mt][nt][reg] + b2n[nt]);
                p[mt*4 + reg][0] = fmaf(h2v, wfs[2*n + 0], p[mt*4 + reg][0]);
                p[mt*4 + reg][1] = fmaf(h2v, wfs[2*n + 1], p[mt*4 + reg][1]);
            }
        }
    #pragma unroll
    for (int o = 1; o < 16; o <<= 1) {
        #pragma unroll
        for (int i = 0; i < 8; ++i) {
            p[i][0] += __shfl_xor(p[i][0], o, 64);
            p[i][1] += __shfl_xor(p[i][1], o, 64);
        }
    }
    if (mrow == 0) {
        #pragma unroll
        for (int mt = 0; mt < 2; ++mt)
            #pragma unroll
            for (int reg = 0; reg < 4; ++reg) {
                const int sample = mt * 16 + qk * 4 + reg;
                oacc[wv_][sample][0] = p[mt*4 + reg][0];
                oacc[wv_][sample][1] = p[mt*4 + reg][1];
            }
    }
    __syncthreads();
    if (t < 32) {
        float o0 = bf[0], o1 = bf[1];
        #pragma unroll
        for (int w = 0; w < 4; ++w) { o0 += oacc[w][t][0]; o1 += oacc[w][t][1]; }
        float4 o4;
        o4.x = o0; o4.y = o1; o4.z = lstd[0]; o4.w = lstd[1];
        *(float4*)&out[(size_t)(blk * 32 + t) * 4] = o4;
    }
}

extern "C" void kernel_launch(void* const* d_in, const int* in_sizes, int n_in,
                              void* d_out, int out_size, void* d_ws, size_t ws_size,
                              hipStream_t stream) {
    const float* obs   = (const float*)d_in[0];
    const float* Wq    = (const float*)d_in[1];
    const float* bq    = (const float*)d_in[2];
    const float* Wk    = (const float*)d_in[3];
    const float* bk    = (const float*)d_in[4];
    const float* Wv    = (const float*)d_in[5];
    const float* bv    = (const float*)d_in[6];
    const float* v_att = (const float*)d_in[7];
    const float* temp  = (const float*)d_in[8];
    const float* ln_g  = (const float*)d_in[9];
    const float* ln_b  = (const float*)d_in[10];
    const float* W1    = (const float*)d_in[11];
    const float* b1    = (const float*)d_in[12];
    const float* W2    = (const float*)d_in[13];
    const float* b2    = (const float*)d_in[14];
    const float* Wf    = (const float*)d_in[15];
    const float* bf    = (const float*)d_in[16];
    const float* lstd  = (const float*)d_in[17];

    float* xbuf = (float*)d_ws;   // B x 22 normalized features (2.88 MB)
    float* outf = (float*)d_out;

    attn_ln_kernel<<<NBATCH / 16, 256, 0, stream>>>(
        obs, Wq, bq, Wk, bk, Wv, bv, v_att, temp, ln_g, ln_b, xbuf);
    mlp_kernel<<<NBATCH / 32, 256, 0, stream>>>(
        xbuf, W1, b1, W2, b2, Wf, bf, lstd, outf);
}

// Round 15
// 92.952 us; speedup vs baseline: 1.6015x; 1.1518x over previous
//
#include <hip/hip_runtime.h>
#include <math.h>

// Problem constants
#define NBATCH   32768
#define OWN_DIM  7
#define INTR_DIM 5
#define N_HEADS  3
#define HEAD_DIM 5
#define N_INTR   256
#define ROWLEN   1287   // OWN_DIM + N_INTR*INTR_DIM
#define XDIM     22     // OWN_DIM + N_HEADS*HEAD_DIM
#define H1DIM    256
#define H2DIM    256

typedef __attribute__((ext_vector_type(8))) short bf16x8;
typedef __attribute__((ext_vector_type(4))) float f32x4;

__device__ __forceinline__ float leaky02(float x) {
    return fmaxf(x, 0.2f * x);
}

__device__ __forceinline__ unsigned short f2bf_rne(float f) {
    unsigned u = __float_as_uint(f);
    return (unsigned short)((u + 0x7FFFu + ((u >> 16) & 1u)) >> 16);
}

// Opaque per-value register pin: load feeding it cannot be sunk/rematerialized
// below this point; consumers cannot float above. Forces true VGPR residency.
#define PIN(x) asm volatile("" : "+v"(x))

// ---------------- Kernel A: attention + layernorm -> x (B x 22) ----------------
// 4 samples/wave (16 lanes each), direct strided loads (86us baseline, r12).
// r14 synthesis: load cost ~70us is EXPOSED LATENCY (corrected TA math = 21us,
// not request-bound; occupancy ~40%, distance-1 loads). All staging variants
// fail on the compiler's 64-VGPR plateau (remat/sink r8, spill r11/r14).
// This round: 4-item batched prefetch pipeline with asm-pinned buffers —
// remat-proof (opaque asm), ~520 issue-cyc prefetch distance, and the pins
// force VGPR past 64 onto the 128/4-wave step that launch_bounds(256,4) allows.
__global__ __launch_bounds__(256, 4) void attn_ln_kernel(
    const float* __restrict__ obs,
    const float* __restrict__ Wq, const float* __restrict__ bq,
    const float* __restrict__ Wk, const float* __restrict__ bk,
    const float* __restrict__ Wv, const float* __restrict__ bv,
    const float* __restrict__ v_att, const float* __restrict__ temp,
    const float* __restrict__ ln_g, const float* __restrict__ ln_b,
    float* __restrict__ xout)
{
    const int wid  = threadIdx.x >> 6;
    const int lane = threadIdx.x & 63;
    const int grp  = lane >> 4;     // sample slot within wave (0..3)
    const int gl   = lane & 15;     // lane within 16-lane sample group
    const int s    = blockIdx.x * 16 + wid * 4 + grp;
    const float* row = obs + (size_t)s * ROWLEN;

    const float fac = fabsf(temp[0]) * 0.4472135954999579f;      // |T|/sqrt(5)
    const float facl2e = fac * 1.4426950408889634f;              // * log2e
    const float TL2E = 2.885390081777927f;                       // 2*log2e

    // own[0..6] of this lane's sample (16-way broadcast per group)
    float own[OWN_DIM];
    #pragma unroll
    for (int o = 0; o < OWN_DIM; ++o) own[o] = row[o];

    // per-head score constants: va2 = -2*facl2e*v_att, vasum = facl2e*sum(v_att)
    float va2[N_HEADS][HEAD_DIM], vasum[N_HEADS];
    #pragma unroll
    for (int h = 0; h < N_HEADS; ++h) {
        float ssum = 0.0f;
        #pragma unroll
        for (int d = 0; d < HEAD_DIM; ++d) {
            float v = v_att[h*HEAD_DIM + d];
            ssum += v;
            va2[h][d] = v * (-2.0f * facl2e);
        }
        vasum[h] = ssum * facl2e;
    }

    // qb[h][d] = q + bk for this lane's sample
    float qb[N_HEADS][HEAD_DIM];
    #pragma unroll
    for (int h = 0; h < N_HEADS; ++h)
        #pragma unroll
        for (int d = 0; d < HEAD_DIM; ++d) {
            float a = bq[h*HEAD_DIM + d] + bk[h*HEAD_DIM + d];
            #pragma unroll
            for (int o = 0; o < OWN_DIM; ++o)
                a = fmaf(own[o], Wq[h*OWN_DIM*HEAD_DIM + o*HEAD_DIM + d], a);
            qb[h][d] = a;
        }

    // accumulators: svp[h][i] = sum_n e_n*xi_n[i], es[h] = sum_n e_n
    float svp[N_HEADS][INTR_DIM] = {};
    float es[N_HEADS] = {};

    // batch load: items r0..r0+3 (n = gl + 16*r), 20 scalar dwords -> buf
    #define LOAD_BATCH(buf, r0)                                              \
        {                                                                    \
            _Pragma("unroll")                                                \
            for (int k = 0; k < 4; ++k) {                                    \
                const float* it = row + OWN_DIM + (gl + 16*((r0)+k)) * INTR_DIM; \
                _Pragma("unroll")                                            \
                for (int i = 0; i < INTR_DIM; ++i) (buf)[k*5+i] = it[i];     \
            }                                                                \
            _Pragma("unroll")                                                \
            for (int j = 0; j < 20; ++j) PIN((buf)[j]);                      \
        }

    // batch compute: consume 4 items from buf
    #define COMP_BATCH(buf)                                                  \
        {                                                                    \
            _Pragma("unroll")                                                \
            for (int k = 0; k < 4; ++k) {                                    \
                const float* xi = &(buf)[k*5];                               \
                float asum = fabsf(xi[0]) + fabsf(xi[1]) + fabsf(xi[2])      \
                           + fabsf(xi[3]) + fabsf(xi[4]);                    \
                const float npf = (asum < 1e-6f) ? 0.0f : 1.0f;              \
                _Pragma("unroll")                                            \
                for (int h = 0; h < N_HEADS; ++h) {                          \
                    float dot = vasum[h];                                    \
                    _Pragma("unroll")                                        \
                    for (int d = 0; d < HEAD_DIM; ++d) {                     \
                        float t = qb[h][d];                                  \
                        _Pragma("unroll")                                    \
                        for (int i = 0; i < INTR_DIM; ++i)                   \
                            t = fmaf(xi[i], Wk[h*INTR_DIM*HEAD_DIM + i*HEAD_DIM + d], t); \
                        float e = __builtin_amdgcn_exp2f(t * TL2E);          \
                        float rc = __builtin_amdgcn_rcpf(e + 1.0f);          \
                        dot = fmaf(va2[h][d], rc, dot);                      \
                    }                                                        \
                    float e = npf * __builtin_amdgcn_exp2f(dot);             \
                    es[h] += e;                                              \
                    _Pragma("unroll")                                        \
                    for (int i = 0; i < INTR_DIM; ++i)                       \
                        svp[h][i] = fmaf(e, xi[i], svp[h][i]);               \
                }                                                            \
            }                                                                \
        }

    // software pipeline, distance = 4 items (~520 issue-cyc), named buffers
    float xa[20], xb[20];
    LOAD_BATCH(xa, 0);
    LOAD_BATCH(xb, 4);      // prefetch batch 1 before computing batch 0
    COMP_BATCH(xa);
    LOAD_BATCH(xa, 8);      // prefetch batch 2 before computing batch 1
    COMP_BATCH(xb);
    LOAD_BATCH(xb, 12);     // prefetch batch 3 before computing batch 2
    COMP_BATCH(xa);
    COMP_BATCH(xb);

    #undef LOAD_BATCH
    #undef COMP_BATCH

    // 4-level butterfly within each 16-lane group (18 values)
    #pragma unroll
    for (int o = 1; o < 16; o <<= 1) {
        #pragma unroll
        for (int h = 0; h < N_HEADS; ++h) {
            es[h] += __shfl_xor(es[h], o, 64);
            #pragma unroll
            for (int i = 0; i < INTR_DIM; ++i)
                svp[h][i] += __shfl_xor(svp[h][i], o, 64);
        }
    }

    // normalize + deferred V projection: ctx = (svp/es) @ Wv + bv*live
    float ctx[N_HEADS][HEAD_DIM];
    #pragma unroll
    for (int h = 0; h < N_HEADS; ++h) {
        const float live = (es[h] > 0.0f) ? 1.0f : 0.0f;
        const float rinv = live * __builtin_amdgcn_rcpf(es[h]);
        float svn[INTR_DIM];
        #pragma unroll
        for (int i = 0; i < INTR_DIM; ++i) svn[i] = svp[h][i] * rinv;
        #pragma unroll
        for (int d = 0; d < HEAD_DIM; ++d) {
            float c = bv[h*HEAD_DIM + d] * live;
            #pragma unroll
            for (int i = 0; i < INTR_DIM; ++i)
                c = fmaf(svn[i], Wv[h*INTR_DIM*HEAD_DIM + i*HEAD_DIM + d], c);
            ctx[h][d] = c;
        }
    }

    // layernorm over x = [own(7), ctx(15)] (redundant across the 16 group lanes)
    float sum = 0.0f;
    #pragma unroll
    for (int o = 0; o < OWN_DIM; ++o) sum += own[o];
    #pragma unroll
    for (int h = 0; h < N_HEADS; ++h)
        #pragma unroll
        for (int d = 0; d < HEAD_DIM; ++d) sum += ctx[h][d];
    const float mu = sum * (1.0f / 22.0f);
    float var = 0.0f;
    #pragma unroll
    for (int o = 0; o < OWN_DIM; ++o) { float dd = own[o] - mu; var += dd*dd; }
    #pragma unroll
    for (int h = 0; h < N_HEADS; ++h)
        #pragma unroll
        for (int d = 0; d < HEAD_DIM; ++d) { float dd = ctx[h][d] - mu; var += dd*dd; }
    var *= (1.0f / 22.0f);
    const float rs = rsqrtf(var + 1e-5f);

    // lane gl writes elements gl and gl+16 (if <22) via static select chains
    float xv0 = own[0];
    #pragma unroll
    for (int o = 1; o < OWN_DIM; ++o) xv0 = (gl == o) ? own[o] : xv0;
    #pragma unroll
    for (int j = 0; j < 15; ++j) xv0 = (gl == OWN_DIM + j) ? ctx[j/5][j%5] : xv0;
    float xv1 = ctx[1][4];                    // element 16 -> ctx j=9
    #pragma unroll
    for (int j = 10; j < 15; ++j) xv1 = (gl == j - 9) ? ctx[j/5][j%5] : xv1;

    float* xo = xout + (size_t)s * XDIM;
    xo[gl] = (xv0 - mu) * rs * ln_g[gl] + ln_b[gl];
    if (gl < XDIM - 16) {
        xo[16 + gl] = (xv1 - mu) * rs * ln_g[16 + gl] + ln_b[16 + gl];
    }
}

// ---------------- Kernel B: MLP 22->256->256->2 (+log_std) ----------------
// (unchanged — 4.4 us, MFMA layer-2, verified round 5)
__global__ __launch_bounds__(256) void mlp_kernel(
    const float* __restrict__ x,
    const float* __restrict__ W1, const float* __restrict__ b1,
    const float* __restrict__ W2, const float* __restrict__ b2,
    const float* __restrict__ Wf, const float* __restrict__ bf,
    const float* __restrict__ lstd, float* __restrict__ out)
{
    __shared__ __align__(16) float xs[32 * XDIM];
    __shared__ __align__(16) unsigned char h1b[32 * 256 * 2];
    __shared__ __align__(16) unsigned char w2b[256 * 64 * 2];
    __shared__ __align__(16) float wfs[H2DIM * 2];
    __shared__ float oacc[4][32][2];

    const int t   = threadIdx.x;
    const int blk = blockIdx.x;

    for (int i = t; i < 32 * XDIM; i += 256) xs[i] = x[(size_t)blk * 32 * XDIM + i];
    for (int i = t; i < H2DIM * 2; i += 256) wfs[i] = Wf[i];

    float w1r[XDIM];
    #pragma unroll
    for (int i = 0; i < XDIM; ++i) w1r[i] = W1[i * H1DIM + t];
    const float b1t = b1[t];
    __syncthreads();
    for (int e = 0; e < 32; ++e) {
        float a = b1t;
        #pragma unroll
        for (int i = 0; i < XDIM; ++i) a += xs[e * XDIM + i] * w1r[i];
        a = leaky02(a);
        int byte = e * 512 + t * 2;
        byte ^= ((e & 7) << 4);
        *(unsigned short*)(h1b + byte) = f2bf_rne(a);
    }

    const int wv_  = t >> 6;
    const int lane = t & 63;
    const int mrow = lane & 15;
    const int qk   = lane >> 4;

    f32x4 acc[2][4];
    #pragma unroll
    for (int mt = 0; mt < 2; ++mt)
        #pragma unroll
        for (int nt = 0; nt < 4; ++nt)
            acc[mt][nt] = (f32x4){0.f, 0.f, 0.f, 0.f};

    for (int kc = 0; kc < 4; ++kc) {
        __syncthreads();
        {
            const int n = t;
            #pragma unroll
            for (int k8 = 0; k8 < 64; k8 += 8) {
                bf16x8 v;
                #pragma unroll
                for (int j = 0; j < 8; ++j) {
                    float w = W2[(size_t)(kc * 64 + k8 + j) * H2DIM + n];
                    v[j] = (short)f2bf_rne(w);
                }
                int byte = n * 128 + k8 * 2;
                byte ^= ((n & 7) << 4);
                *(bf16x8*)(w2b + byte) = v;
            }
        }
        __syncthreads();
        #pragma unroll
        for (int ks = 0; ks < 2; ++ks) {
            const int klocal = ks * 32;
            const int kglob  = kc * 64 + klocal;
            bf16x8 afrag[2], bfrag[4];
            #pragma unroll
            for (int mt = 0; mt < 2; ++mt) {
                const int rowi = mt * 16 + mrow;
                int byte = rowi * 512 + (kglob + 8 * qk) * 2;
                byte ^= ((rowi & 7) << 4);
                afrag[mt] = *(const bf16x8*)(h1b + byte);
            }
            #pragma unroll
            for (int nt = 0; nt < 4; ++nt) {
                const int col = wv_ * 64 + nt * 16 + mrow;
                int byte = col * 128 + (klocal + 8 * qk) * 2;
                byte ^= ((col & 7) << 4);
                bfrag[nt] = *(const bf16x8*)(w2b + byte);
            }
            #pragma unroll
            for (int mt = 0; mt < 2; ++mt)
                #pragma unroll
                for (int nt = 0; nt < 4; ++nt)
                    acc[mt][nt] = __builtin_amdgcn_mfma_f32_16x16x32_bf16(
                        afrag[mt], bfrag[nt], acc[mt][nt], 0, 0, 0);
        }
    }

    float b2n[4];
    #pragma unroll
    for (int nt = 0; nt < 4; ++nt) b2n[nt] = b2[wv_ * 64 + nt * 16 + mrow];

    float p[8][2];
    #pragma unroll
    for (int i = 0; i < 8; ++i) { p[i][0] = 0.f; p[i][1] = 0.f; }
    #pragma unroll
    for (int mt = 0; mt < 2; ++mt)
        #pragma unroll
        for (int nt = 0; nt < 4; ++nt) {
            const int n = wv_ * 64 + nt * 16 + mrow;
            #pragma unroll
            for (int reg = 0; reg < 4; ++reg) {
                float h2v = leaky02(acc[mt][nt][reg] + b2n[nt]);
                p[mt*4 + reg][0] = fmaf(h2v, wfs[2*n + 0], p[mt*4 + reg][0]);
                p[mt*4 + reg][1] = fmaf(h2v, wfs[2*n + 1], p[mt*4 + reg][1]);
            }
        }
    #pragma unroll
    for (int o = 1; o < 16; o <<= 1) {
        #pragma unroll
        for (int i = 0; i < 8; ++i) {
            p[i][0] += __shfl_xor(p[i][0], o, 64);
            p[i][1] += __shfl_xor(p[i][1], o, 64);
        }
    }
    if (mrow == 0) {
        #pragma unroll
        for (int mt = 0; mt < 2; ++mt)
            #pragma unroll
            for (int reg = 0; reg < 4; ++reg) {
                const int sample = mt * 16 + qk * 4 + reg;
                oacc[wv_][sample][0] = p[mt*4 + reg][0];
                oacc[wv_][sample][1] = p[mt*4 + reg][1];
            }
    }
    __syncthreads();
    if (t < 32) {
        float o0 = bf[0], o1 = bf[1];
        #pragma unroll
        for (int w = 0; w < 4; ++w) { o0 += oacc[w][t][0]; o1 += oacc[w][t][1]; }
        float4 o4;
        o4.x = o0; o4.y = o1; o4.z = lstd[0]; o4.w = lstd[1];
        *(float4*)&out[(size_t)(blk * 32 + t) * 4] = o4;
    }
}

extern "C" void kernel_launch(void* const* d_in, const int* in_sizes, int n_in,
                              void* d_out, int out_size, void* d_ws, size_t ws_size,
                              hipStream_t stream) {
    const float* obs   = (const float*)d_in[0];
    const float* Wq    = (const float*)d_in[1];
    const float* bq    = (const float*)d_in[2];
    const float* Wk    = (const float*)d_in[3];
    const float* bk    = (const float*)d_in[4];
    const float* Wv    = (const float*)d_in[5];
    const float* bv    = (const float*)d_in[6];
    const float* v_att = (const float*)d_in[7];
    const float* temp  = (const float*)d_in[8];
    const float* ln_g  = (const float*)d_in[9];
    const float* ln_b  = (const float*)d_in[10];
    const float* W1    = (const float*)d_in[11];
    const float* b1    = (const float*)d_in[12];
    const float* W2    = (const float*)d_in[13];
    const float* b2    = (const float*)d_in[14];
    const float* Wf    = (const float*)d_in[15];
    const float* bf    = (const float*)d_in[16];
    const float* lstd  = (const float*)d_in[17];

    float* xbuf = (float*)d_ws;   // B x 22 normalized features (2.88 MB)
    float* outf = (float*)d_out;

    attn_ln_kernel<<<NBATCH / 16, 256, 0, stream>>>(
        obs, Wq, bq, Wk, bk, Wv, bv, v_att, temp, ln_g, ln_b, xbuf);
    mlp_kernel<<<NBATCH / 32, 256, 0, stream>>>(
        xbuf, W1, b1, W2, b2, Wf, bf, lstd, outf);
}

// Round 16
// 92.743 us; speedup vs baseline: 1.6051x; 1.0023x over previous
//
#include <hip/hip_runtime.h>
#include <math.h>

// Problem constants
#define NBATCH   32768
#define OWN_DIM  7
#define INTR_DIM 5
#define N_HEADS  3
#define HEAD_DIM 5
#define N_INTR   256
#define ROWLEN   1287   // OWN_DIM + N_INTR*INTR_DIM
#define XDIM     22     // OWN_DIM + N_HEADS*HEAD_DIM
#define H1DIM    256
#define H2DIM    256

typedef __attribute__((ext_vector_type(8))) short bf16x8;
typedef __attribute__((ext_vector_type(4))) float f32x4;

__device__ __forceinline__ float leaky02(float x) {
    return fmaxf(x, 0.2f * x);
}

__device__ __forceinline__ unsigned short f2bf_rne(float f) {
    unsigned u = __float_as_uint(f);
    return (unsigned short)((u + 0x7FFFu + ((u >> 16) & 1u)) >> 16);
}

// ---------------- Kernel A: attention + layernorm -> x (B x 22) ----------------
// 4 samples/wave (16 lanes each), direct strided loads — the proven 86us
// structure (r7/r12), ONE change: amdgpu_waves_per_eu(4,4).
// Rationale (r15 synthesis): the backend pins VGPR=64 (8-wave occupancy
// target) in every variant, spilling/de-pipelining anything larger.
// __launch_bounds__ only sets the MIN waves/EU; setting max=4 via the
// attribute gives the scheduler a 128-VGPR budget and makes it plan for
// 4 waves/EU -> aggressive load hoisting (ILP) instead of reg-minimization.
__global__ __attribute__((amdgpu_waves_per_eu(4, 4))) __launch_bounds__(256)
void attn_ln_kernel(
    const float* __restrict__ obs,
    const float* __restrict__ Wq, const float* __restrict__ bq,
    const float* __restrict__ Wk, const float* __restrict__ bk,
    const float* __restrict__ Wv, const float* __restrict__ bv,
    const float* __restrict__ v_att, const float* __restrict__ temp,
    const float* __restrict__ ln_g, const float* __restrict__ ln_b,
    float* __restrict__ xout)
{
    const int wid  = threadIdx.x >> 6;
    const int lane = threadIdx.x & 63;
    const int grp  = lane >> 4;     // sample slot within wave (0..3)
    const int gl   = lane & 15;     // lane within 16-lane sample group
    const int s    = blockIdx.x * 16 + wid * 4 + grp;
    const float* row = obs + (size_t)s * ROWLEN;

    const float fac = fabsf(temp[0]) * 0.4472135954999579f;      // |T|/sqrt(5)
    const float facl2e = fac * 1.4426950408889634f;              // * log2e
    const float TL2E = 2.885390081777927f;                       // 2*log2e

    // own[0..6] of this lane's sample (16-way broadcast per group)
    float own[OWN_DIM];
    #pragma unroll
    for (int o = 0; o < OWN_DIM; ++o) own[o] = row[o];

    // per-head score constants: va2 = -2*facl2e*v_att, vasum = facl2e*sum(v_att)
    float va2[N_HEADS][HEAD_DIM], vasum[N_HEADS];
    #pragma unroll
    for (int h = 0; h < N_HEADS; ++h) {
        float ssum = 0.0f;
        #pragma unroll
        for (int d = 0; d < HEAD_DIM; ++d) {
            float v = v_att[h*HEAD_DIM + d];
            ssum += v;
            va2[h][d] = v * (-2.0f * facl2e);
        }
        vasum[h] = ssum * facl2e;
    }

    // qb[h][d] = q + bk for this lane's sample
    float qb[N_HEADS][HEAD_DIM];
    #pragma unroll
    for (int h = 0; h < N_HEADS; ++h)
        #pragma unroll
        for (int d = 0; d < HEAD_DIM; ++d) {
            float a = bq[h*HEAD_DIM + d] + bk[h*HEAD_DIM + d];
            #pragma unroll
            for (int o = 0; o < OWN_DIM; ++o)
                a = fmaf(own[o], Wq[h*OWN_DIM*HEAD_DIM + o*HEAD_DIM + d], a);
            qb[h][d] = a;
        }

    // accumulators: svp[h][i] = sum_n e_n*xi_n[i], es[h] = sum_n e_n
    float svp[N_HEADS][INTR_DIM] = {};
    float es[N_HEADS] = {};

    // 16 items per lane: n = gl + 16*r (fully unrolled; with the 128-VGPR
    // budget the scheduler can hoist many item loads ahead of their use)
    #pragma unroll
    for (int r = 0; r < 16; ++r) {
        const float* it = row + OWN_DIM + (gl + 16*r) * INTR_DIM;
        float xi[INTR_DIM];
        #pragma unroll
        for (int i = 0; i < INTR_DIM; ++i) xi[i] = it[i];
        float asum = fabsf(xi[0]) + fabsf(xi[1]) + fabsf(xi[2])
                   + fabsf(xi[3]) + fabsf(xi[4]);
        const float npf = (asum < 1e-6f) ? 0.0f : 1.0f;
        #pragma unroll
        for (int h = 0; h < N_HEADS; ++h) {
            float dot = vasum[h];
            #pragma unroll
            for (int d = 0; d < HEAD_DIM; ++d) {
                float t = qb[h][d];
                #pragma unroll
                for (int i = 0; i < INTR_DIM; ++i)
                    t = fmaf(xi[i], Wk[h*INTR_DIM*HEAD_DIM + i*HEAD_DIM + d], t);
                float e = __builtin_amdgcn_exp2f(t * TL2E);
                float rc = __builtin_amdgcn_rcpf(e + 1.0f);
                dot = fmaf(va2[h][d], rc, dot);     // == facl2e*sum va*tanh
            }
            float e = npf * __builtin_amdgcn_exp2f(dot);
            es[h] += e;
            #pragma unroll
            for (int i = 0; i < INTR_DIM; ++i)
                svp[h][i] = fmaf(e, xi[i], svp[h][i]);
        }
    }

    // 4-level butterfly within each 16-lane group (18 values)
    #pragma unroll
    for (int o = 1; o < 16; o <<= 1) {
        #pragma unroll
        for (int h = 0; h < N_HEADS; ++h) {
            es[h] += __shfl_xor(es[h], o, 64);
            #pragma unroll
            for (int i = 0; i < INTR_DIM; ++i)
                svp[h][i] += __shfl_xor(svp[h][i], o, 64);
        }
    }

    // normalize + deferred V projection: ctx = (svp/es) @ Wv + bv*live
    float ctx[N_HEADS][HEAD_DIM];
    #pragma unroll
    for (int h = 0; h < N_HEADS; ++h) {
        const float live = (es[h] > 0.0f) ? 1.0f : 0.0f;
        const float rinv = live * __builtin_amdgcn_rcpf(es[h]);
        float svn[INTR_DIM];
        #pragma unroll
        for (int i = 0; i < INTR_DIM; ++i) svn[i] = svp[h][i] * rinv;
        #pragma unroll
        for (int d = 0; d < HEAD_DIM; ++d) {
            float c = bv[h*HEAD_DIM + d] * live;
            #pragma unroll
            for (int i = 0; i < INTR_DIM; ++i)
                c = fmaf(svn[i], Wv[h*INTR_DIM*HEAD_DIM + i*HEAD_DIM + d], c);
            ctx[h][d] = c;
        }
    }

    // layernorm over x = [own(7), ctx(15)] (redundant across the 16 group lanes)
    float sum = 0.0f;
    #pragma unroll
    for (int o = 0; o < OWN_DIM; ++o) sum += own[o];
    #pragma unroll
    for (int h = 0; h < N_HEADS; ++h)
        #pragma unroll
        for (int d = 0; d < HEAD_DIM; ++d) sum += ctx[h][d];
    const float mu = sum * (1.0f / 22.0f);
    float var = 0.0f;
    #pragma unroll
    for (int o = 0; o < OWN_DIM; ++o) { float dd = own[o] - mu; var += dd*dd; }
    #pragma unroll
    for (int h = 0; h < N_HEADS; ++h)
        #pragma unroll
        for (int d = 0; d < HEAD_DIM; ++d) { float dd = ctx[h][d] - mu; var += dd*dd; }
    var *= (1.0f / 22.0f);
    const float rs = rsqrtf(var + 1e-5f);

    // lane gl writes elements gl and gl+16 (if <22) via static select chains
    float xv0 = own[0];
    #pragma unroll
    for (int o = 1; o < OWN_DIM; ++o) xv0 = (gl == o) ? own[o] : xv0;
    #pragma unroll
    for (int j = 0; j < 15; ++j) xv0 = (gl == OWN_DIM + j) ? ctx[j/5][j%5] : xv0;
    float xv1 = ctx[1][4];                    // element 16 -> ctx j=9
    #pragma unroll
    for (int j = 10; j < 15; ++j) xv1 = (gl == j - 9) ? ctx[j/5][j%5] : xv1;

    float* xo = xout + (size_t)s * XDIM;
    xo[gl] = (xv0 - mu) * rs * ln_g[gl] + ln_b[gl];
    if (gl < XDIM - 16) {
        xo[16 + gl] = (xv1 - mu) * rs * ln_g[16 + gl] + ln_b[16 + gl];
    }
}

// ---------------- Kernel B: MLP 22->256->256->2 (+log_std) ----------------
// (unchanged — 4.4 us, MFMA layer-2, verified round 5)
__global__ __launch_bounds__(256) void mlp_kernel(
    const float* __restrict__ x,
    const float* __restrict__ W1, const float* __restrict__ b1,
    const float* __restrict__ W2, const float* __restrict__ b2,
    const float* __restrict__ Wf, const float* __restrict__ bf,
    const float* __restrict__ lstd, float* __restrict__ out)
{
    __shared__ __align__(16) float xs[32 * XDIM];
    __shared__ __align__(16) unsigned char h1b[32 * 256 * 2];
    __shared__ __align__(16) unsigned char w2b[256 * 64 * 2];
    __shared__ __align__(16) float wfs[H2DIM * 2];
    __shared__ float oacc[4][32][2];

    const int t   = threadIdx.x;
    const int blk = blockIdx.x;

    for (int i = t; i < 32 * XDIM; i += 256) xs[i] = x[(size_t)blk * 32 * XDIM + i];
    for (int i = t; i < H2DIM * 2; i += 256) wfs[i] = Wf[i];

    float w1r[XDIM];
    #pragma unroll
    for (int i = 0; i < XDIM; ++i) w1r[i] = W1[i * H1DIM + t];
    const float b1t = b1[t];
    __syncthreads();
    for (int e = 0; e < 32; ++e) {
        float a = b1t;
        #pragma unroll
        for (int i = 0; i < XDIM; ++i) a += xs[e * XDIM + i] * w1r[i];
        a = leaky02(a);
        int byte = e * 512 + t * 2;
        byte ^= ((e & 7) << 4);
        *(unsigned short*)(h1b + byte) = f2bf_rne(a);
    }

    const int wv_  = t >> 6;
    const int lane = t & 63;
    const int mrow = lane & 15;
    const int qk   = lane >> 4;

    f32x4 acc[2][4];
    #pragma unroll
    for (int mt = 0; mt < 2; ++mt)
        #pragma unroll
        for (int nt = 0; nt < 4; ++nt)
            acc[mt][nt] = (f32x4){0.f, 0.f, 0.f, 0.f};

    for (int kc = 0; kc < 4; ++kc) {
        __syncthreads();
        {
            const int n = t;
            #pragma unroll
            for (int k8 = 0; k8 < 64; k8 += 8) {
                bf16x8 v;
                #pragma unroll
                for (int j = 0; j < 8; ++j) {
                    float w = W2[(size_t)(kc * 64 + k8 + j) * H2DIM + n];
                    v[j] = (short)f2bf_rne(w);
                }
                int byte = n * 128 + k8 * 2;
                byte ^= ((n & 7) << 4);
                *(bf16x8*)(w2b + byte) = v;
            }
        }
        __syncthreads();
        #pragma unroll
        for (int ks = 0; ks < 2; ++ks) {
            const int klocal = ks * 32;
            const int kglob  = kc * 64 + klocal;
            bf16x8 afrag[2], bfrag[4];
            #pragma unroll
            for (int mt = 0; mt < 2; ++mt) {
                const int rowi = mt * 16 + mrow;
                int byte = rowi * 512 + (kglob + 8 * qk) * 2;
                byte ^= ((rowi & 7) << 4);
                afrag[mt] = *(const bf16x8*)(h1b + byte);
            }
            #pragma unroll
            for (int nt = 0; nt < 4; ++nt) {
                const int col = wv_ * 64 + nt * 16 + mrow;
                int byte = col * 128 + (klocal + 8 * qk) * 2;
                byte ^= ((col & 7) << 4);
                bfrag[nt] = *(const bf16x8*)(w2b + byte);
            }
            #pragma unroll
            for (int mt = 0; mt < 2; ++mt)
                #pragma unroll
                for (int nt = 0; nt < 4; ++nt)
                    acc[mt][nt] = __builtin_amdgcn_mfma_f32_16x16x32_bf16(
                        afrag[mt], bfrag[nt], acc[mt][nt], 0, 0, 0);
        }
    }

    float b2n[4];
    #pragma unroll
    for (int nt = 0; nt < 4; ++nt) b2n[nt] = b2[wv_ * 64 + nt * 16 + mrow];

    float p[8][2];
    #pragma unroll
    for (int i = 0; i < 8; ++i) { p[i][0] = 0.f; p[i][1] = 0.f; }
    #pragma unroll
    for (int mt = 0; mt < 2; ++mt)
        #pragma unroll
        for (int nt = 0; nt < 4; ++nt) {
            const int n = wv_ * 64 + nt * 16 + mrow;
            #pragma unroll
            for (int reg = 0; reg < 4; ++reg) {
                float h2v = leaky02(acc[mt][nt][reg] + b2n[nt]);
                p[mt*4 + reg][0] = fmaf(h2v, wfs[2*n + 0], p[mt*4 + reg][0]);
                p[mt*4 + reg][1] = fmaf(h2v, wfs[2*n + 1], p[mt*4 + reg][1]);
            }
        }
    #pragma unroll
    for (int o = 1; o < 16; o <<= 1) {
        #pragma unroll
        for (int i = 0; i < 8; ++i) {
            p[i][0] += __shfl_xor(p[i][0], o, 64);
            p[i][1] += __shfl_xor(p[i][1], o, 64);
        }
    }
    if (mrow == 0) {
        #pragma unroll
        for (int mt = 0; mt < 2; ++mt)
            #pragma unroll
            for (int reg = 0; reg < 4; ++reg) {
                const int sample = mt * 16 + qk * 4 + reg;
                oacc[wv_][sample][0] = p[mt*4 + reg][0];
                oacc[wv_][sample][1] = p[mt*4 + reg][1];
            }
    }
    __syncthreads();
    if (t < 32) {
        float o0 = bf[0], o1 = bf[1];
        #pragma unroll
        for (int w = 0; w < 4; ++w) { o0 += oacc[w][t][0]; o1 += oacc[w][t][1]; }
        float4 o4;
        o4.x = o0; o4.y = o1; o4.z = lstd[0]; o4.w = lstd[1];
        *(float4*)&out[(size_t)(blk * 32 + t) * 4] = o4;
    }
}

extern "C" void kernel_launch(void* const* d_in, const int* in_sizes, int n_in,
                              void* d_out, int out_size, void* d_ws, size_t ws_size,
                              hipStream_t stream) {
    const float* obs   = (const float*)d_in[0];
    const float* Wq    = (const float*)d_in[1];
    const float* bq    = (const float*)d_in[2];
    const float* Wk    = (const float*)d_in[3];
    const float* bk    = (const float*)d_in[4];
    const float* Wv    = (const float*)d_in[5];
    const float* bv    = (const float*)d_in[6];
    const float* v_att = (const float*)d_in[7];
    const float* temp  = (const float*)d_in[8];
    const float* ln_g  = (const float*)d_in[9];
    const float* ln_b  = (const float*)d_in[10];
    const float* W1    = (const float*)d_in[11];
    const float* b1    = (const float*)d_in[12];
    const float* W2    = (const float*)d_in[13];
    const float* b2    = (const float*)d_in[14];
    const float* Wf    = (const float*)d_in[15];
    const float* bf    = (const float*)d_in[16];
    const float* lstd  = (const float*)d_in[17];

    float* xbuf = (float*)d_ws;   // B x 22 normalized features (2.88 MB)
    float* outf = (float*)d_out;

    attn_ln_kernel<<<NBATCH / 16, 256, 0, stream>>>(
        obs, Wq, bq, Wk, bk, Wv, bv, v_att, temp, ln_g, ln_b, xbuf);
    mlp_kernel<<<NBATCH / 32, 256, 0, stream>>>(
        xbuf, W1, b1, W2, b2, Wf, bf, lstd, outf);
}